// Round 3
// baseline (5664.575 us; speedup 1.0000x reference)
//
#include <hip/hip_runtime.h>
#include <hip/hip_bf16.h>
#include <cstdint>
#include <cstddef>

// ============================================================================
// LSTM (seq_len=1, h0=c0=0) -> 3 GEMMs + elementwise:
//   L1 : gates1 = x  @ W_ih1^T (+b1)   [8192,1024] x [8192,1024]^T  (i,g,o only)
//   L2 : gates2 = h1 @ W_ih2^T (+b2)   K=2048
//   CLS: out    = h2 @ W_cls^T + b_cls [8192,1000]
// f-gate skipped (c0=0 => f*c0=0). W_hh1/W_hh2 unused (h0=0).
// fp32 emulated as bf16 hi+lo split, 3 MFMA products -> rel err ~2^-17.
//
// R3 change: LDS bank-conflict fix. R2 used LDP=40 pad (dword stride 20,
// gcd(20,32)=4 => ~4-way conflicts, SQ_LDS_BANK_CONFLICT=8.4e7 = 23% of
// cycles). Now: unpadded 32-col rows + XOR chunk swizzle on BOTH write and
// read (chunk' = chunk ^ ((row>>1)&3)) => every 16-lane phase hits each
// bank exactly 2x (free). LDS 50->40KB => 4 blocks/CU.
// ============================================================================

typedef __bf16 bf16x8 __attribute__((ext_vector_type(8)));
typedef float f32x4 __attribute__((ext_vector_type(4)));

#define DI __device__ __forceinline__

DI unsigned short bf16_rne(float f) {
  unsigned u = __float_as_uint(f);
  unsigned r = (u + 0x7fffu + ((u >> 16) & 1u)) >> 16;
  return (unsigned short)r;
}
DI float bf16_f(unsigned short h) { return __uint_as_float((unsigned)h << 16); }
DI float sigmoid_f(float x) { return 1.0f / (1.0f + __expf(-x)); }
DI float tanh_f(float x) {
  float e = __expf(2.0f * x);
  return (e - 1.0f) / (e + 1.0f);
}

// LDS addressing: row-major [row][32 bf16], 16B chunk index XOR-swizzled by
// row bits. Returns offset in shorts. chunk in 0..3.
DI int swz(int row, int chunk) {
  return row * 32 + (((chunk ^ (row >> 1)) & 3) << 3);
}

// ---------------------------------------------------------------------------
// fp32 -> (bf16 hi, bf16 lo) split, vectorized float4. Memory-bound.
// ---------------------------------------------------------------------------
__global__ void k_split(const float* __restrict__ s, unsigned short* __restrict__ hi,
                        unsigned short* __restrict__ lo, long n4) {
  long i = (long)blockIdx.x * blockDim.x + threadIdx.x;
  long st = (long)gridDim.x * blockDim.x;
  for (; i < n4; i += st) {
    float4 v = ((const float4*)s)[i];
    ushort4 h, l;
    h.x = bf16_rne(v.x); l.x = bf16_rne(v.x - bf16_f(h.x));
    h.y = bf16_rne(v.y); l.y = bf16_rne(v.y - bf16_f(h.y));
    h.z = bf16_rne(v.z); l.z = bf16_rne(v.z - bf16_f(h.z));
    h.w = bf16_rne(v.w); l.w = bf16_rne(v.w - bf16_f(h.w));
    ((ushort4*)hi)[i] = h;
    ((ushort4*)lo)[i] = l;
  }
}

__global__ void k_addbias(const float* __restrict__ a, const float* __restrict__ b,
                          float* __restrict__ o, int n) {
  int i = blockIdx.x * blockDim.x + threadIdx.x;
  if (i < n) o[i] = a[i] + b[i];
}

// ---------------------------------------------------------------------------
// Fused LSTM layer: h = tanh( sigmoid(o) * tanh( sigmoid(i)*tanh(g) ) )
// 128x64 h-tile, 4 waves 2x2, wave tile 64x32 per gate, BK=32.
// ---------------------------------------------------------------------------
#define BM 128
#define BN 64

__global__ __launch_bounds__(256, 4) void k_layer(
    const unsigned short* __restrict__ Ah, const unsigned short* __restrict__ Al,
    const unsigned short* __restrict__ Wh, const unsigned short* __restrict__ Wl,
    const float* __restrict__ bsum,
    unsigned short* __restrict__ Hh, unsigned short* __restrict__ Hl,
    int K, int H) {
  __shared__ alignas(16) unsigned short sAh[BM * 32];      // 8 KB
  __shared__ alignas(16) unsigned short sAl[BM * 32];      // 8 KB
  __shared__ alignas(16) unsigned short sWh[3 * BN * 32];  // 12 KB
  __shared__ alignas(16) unsigned short sWl[3 * BN * 32];  // 12 KB

  const int tid = threadIdx.x;
  const int l = tid & 63;
  const int wid = tid >> 6;
  const int wr = wid >> 1, wc = wid & 1;
  const int lr = l & 15;
  const int lch = l >> 4;  // 16B chunk index along K, 0..3

  const int m0 = blockIdx.x * BM;
  const int n0 = blockIdx.y * BN;

  f32x4 acc[3][4][2] = {};

  for (int k0 = 0; k0 < K; k0 += 32) {
    __syncthreads();  // previous compute done before overwrite
    // --- stage A tile: 128 rows x 32 cols, hi+lo (swizzled write) ---
#pragma unroll
    for (int rep = 0; rep < 2; ++rep) {
      int c = tid + rep * 256;
      int row = c >> 2, ch = c & 3;
      size_t ga = (size_t)(m0 + row) * K + k0 + ch * 8;
      int off = swz(row, ch);
      *(int4*)&sAh[off] = *(const int4*)&Ah[ga];
      *(int4*)&sAl[off] = *(const int4*)&Al[ga];
    }
    // --- stage W tile: 3 gates x 64 rows x 32 cols, hi+lo ---
#pragma unroll
    for (int rep = 0; rep < 3; ++rep) {
      int c = tid + rep * 256;
      int grow = c >> 2, ch = c & 3;
      int gate = grow >> 6, row = grow & 63;
      int gofs = gate ? (gate + 1) * H : 0;  // i:0, g:2H, o:3H
      size_t ga = (size_t)(gofs + n0 + row) * K + k0 + ch * 8;
      int off = swz(grow, ch);
      *(int4*)&sWh[off] = *(const int4*)&Wh[ga];
      *(int4*)&sWl[off] = *(const int4*)&Wl[ga];
    }
    __syncthreads();
    // --- fragments (swizzled read) + MFMA ---
    bf16x8 ah[4], al[4];
#pragma unroll
    for (int m = 0; m < 4; ++m) {
      int off = swz(wr * 64 + m * 16 + lr, lch);
      ah[m] = *(const bf16x8*)&sAh[off];
      al[m] = *(const bf16x8*)&sAl[off];
    }
#pragma unroll
    for (int g = 0; g < 3; ++g) {
      bf16x8 bh[2], bl[2];
#pragma unroll
      for (int n = 0; n < 2; ++n) {
        int off = swz(g * BN + wc * 32 + n * 16 + lr, lch);
        bh[n] = *(const bf16x8*)&sWh[off];
        bl[n] = *(const bf16x8*)&sWl[off];
      }
#pragma unroll
      for (int m = 0; m < 4; ++m)
#pragma unroll
        for (int n = 0; n < 2; ++n) {
          acc[g][m][n] = __builtin_amdgcn_mfma_f32_16x16x32_bf16(ah[m], bh[n], acc[g][m][n], 0, 0, 0);
          acc[g][m][n] = __builtin_amdgcn_mfma_f32_16x16x32_bf16(ah[m], bl[n], acc[g][m][n], 0, 0, 0);
          acc[g][m][n] = __builtin_amdgcn_mfma_f32_16x16x32_bf16(al[m], bh[n], acc[g][m][n], 0, 0, 0);
        }
    }
  }

  // --- epilogue: gates -> h, split h to hi/lo bf16 for the next GEMM ---
  // C/D layout (m89): col = lane&15, row = (lane>>4)*4 + reg
#pragma unroll
  for (int m = 0; m < 4; ++m)
#pragma unroll
    for (int n = 0; n < 2; ++n) {
      int rowl = wr * 64 + m * 16 + (l >> 4) * 4;
      int coll = wc * 32 + n * 16 + lr;
      int col = n0 + coll;
      float bi = bsum[col];
      float bg = bsum[2 * H + col];
      float bo = bsum[3 * H + col];
#pragma unroll
      for (int v = 0; v < 4; ++v) {
        float gi = acc[0][m][n][v] + bi;
        float gg = acc[1][m][n][v] + bg;
        float go = acc[2][m][n][v] + bo;
        float c = sigmoid_f(gi) * tanh_f(gg);          // c = i*g (c0 = 0)
        float h = tanh_f(sigmoid_f(go) * tanh_f(c));   // tanh(o*tanh(c))
        size_t idx = (size_t)(m0 + rowl + v) * H + col;
        unsigned short hh = bf16_rne(h);
        Hh[idx] = hh;
        Hl[idx] = bf16_rne(h - bf16_f(hh));
      }
    }
}

// ---------------------------------------------------------------------------
// Classifier: out = h2 @ W_cls^T + b_cls, fp32 out, N=1000 (guarded)
// ---------------------------------------------------------------------------
__global__ __launch_bounds__(256, 4) void k_cls(
    const unsigned short* __restrict__ Ah, const unsigned short* __restrict__ Al,
    const unsigned short* __restrict__ Wh, const unsigned short* __restrict__ Wl,
    const float* __restrict__ bias, float* __restrict__ out,
    int K, int N) {
  __shared__ alignas(16) unsigned short sAh[BM * 32];
  __shared__ alignas(16) unsigned short sAl[BM * 32];
  __shared__ alignas(16) unsigned short sWh[BN * 32];
  __shared__ alignas(16) unsigned short sWl[BN * 32];

  const int tid = threadIdx.x;
  const int l = tid & 63;
  const int wid = tid >> 6;
  const int wr = wid >> 1, wc = wid & 1;
  const int lr = l & 15;
  const int lch = l >> 4;

  const int m0 = blockIdx.x * BM;
  const int n0 = blockIdx.y * BN;

  f32x4 acc[4][2] = {};

  for (int k0 = 0; k0 < K; k0 += 32) {
    __syncthreads();
#pragma unroll
    for (int rep = 0; rep < 2; ++rep) {
      int c = tid + rep * 256;
      int row = c >> 2, ch = c & 3;
      size_t ga = (size_t)(m0 + row) * K + k0 + ch * 8;
      int off = swz(row, ch);
      *(int4*)&sAh[off] = *(const int4*)&Ah[ga];
      *(int4*)&sAl[off] = *(const int4*)&Al[ga];
    }
    {  // W: 64 rows x 4 chunks = 256 chunks (1 rep), guard rows >= N
      int row = tid >> 2, ch = tid & 3;
      int rg = n0 + row;
      int off = swz(row, ch);
      int4 z = {0, 0, 0, 0};
      if (rg < N) {
        size_t ga = (size_t)rg * K + k0 + ch * 8;
        *(int4*)&sWh[off] = *(const int4*)&Wh[ga];
        *(int4*)&sWl[off] = *(const int4*)&Wl[ga];
      } else {
        *(int4*)&sWh[off] = z;
        *(int4*)&sWl[off] = z;
      }
    }
    __syncthreads();
    bf16x8 ah[4], al[4];
#pragma unroll
    for (int m = 0; m < 4; ++m) {
      int off = swz(wr * 64 + m * 16 + lr, lch);
      ah[m] = *(const bf16x8*)&sAh[off];
      al[m] = *(const bf16x8*)&sAl[off];
    }
    bf16x8 bh[2], bl[2];
#pragma unroll
    for (int n = 0; n < 2; ++n) {
      int off = swz(wc * 32 + n * 16 + lr, lch);
      bh[n] = *(const bf16x8*)&sWh[off];
      bl[n] = *(const bf16x8*)&sWl[off];
    }
#pragma unroll
    for (int m = 0; m < 4; ++m)
#pragma unroll
      for (int n = 0; n < 2; ++n) {
        acc[m][n] = __builtin_amdgcn_mfma_f32_16x16x32_bf16(ah[m], bh[n], acc[m][n], 0, 0, 0);
        acc[m][n] = __builtin_amdgcn_mfma_f32_16x16x32_bf16(ah[m], bl[n], acc[m][n], 0, 0, 0);
        acc[m][n] = __builtin_amdgcn_mfma_f32_16x16x32_bf16(al[m], bh[n], acc[m][n], 0, 0, 0);
      }
  }

#pragma unroll
  for (int m = 0; m < 4; ++m)
#pragma unroll
    for (int n = 0; n < 2; ++n) {
      int rowl = wr * 64 + m * 16 + (l >> 4) * 4;
      int coll = wc * 32 + n * 16 + lr;
      int col = n0 + coll;
      float bv = (col < N) ? bias[col] : 0.0f;
#pragma unroll
      for (int v = 0; v < 4; ++v) {
        if (col < N) {
          out[(size_t)(m0 + rowl + v) * N + col] = acc[m][n][v] + bv;
        }
      }
    }
}

// ---------------------------------------------------------------------------
extern "C" void kernel_launch(void* const* d_in, const int* in_sizes, int n_in,
                              void* d_out, int out_size, void* d_ws, size_t ws_size,
                              hipStream_t stream) {
  const int B = 8192, D = 1024, H = 2048, C = 1000;
  const int FH = 4 * H;

  const float* x   = (const float*)d_in[0];
  const float* W1  = (const float*)d_in[1];
  const float* bi1 = (const float*)d_in[3];
  const float* bh1 = (const float*)d_in[4];
  const float* W2  = (const float*)d_in[5];
  const float* bi2 = (const float*)d_in[7];
  const float* bh2 = (const float*)d_in[8];
  const float* Wc  = (const float*)d_in[9];
  const float* bc  = (const float*)d_in[10];
  float* out = (float*)d_out;

  // workspace layout (bytes, 256B aligned)
  char* ws = (char*)d_ws;
  size_t off = 0;
  auto take = [&](size_t bytes) -> char* {
    char* p = ws + off;
    off = (off + bytes + 255) & ~(size_t)255;
    return p;
  };
  const size_t nBD = (size_t)B * D;   // 8.39M
  const size_t nW1 = (size_t)FH * D;  // 8.39M
  const size_t nW2 = (size_t)FH * H;  // 16.8M
  const size_t nWC = (size_t)C * H;   // 2.05M
  const size_t nH  = (size_t)B * H;   // 16.8M

  // x + W1 splits are dead after L1; h2 (written by L2, read by CLS) aliases
  // that region. Stream ordering guarantees no hazard.
  char* region0 = take(nBD * 2 * 2 + nW1 * 2 * 2 + 1024);  // xh,xl,W1h,W1l | h2h,h2l
  unsigned short* xh  = (unsigned short*)region0;
  unsigned short* xl  = xh + nBD;
  unsigned short* W1h = xl + nBD;
  unsigned short* W1l = W1h + nW1;
  unsigned short* h2h = (unsigned short*)region0;          // alias (after L1)
  unsigned short* h2l = h2h + nH;

  unsigned short* W2h = (unsigned short*)take(nW2 * 2);
  unsigned short* W2l = (unsigned short*)take(nW2 * 2);
  unsigned short* Wch = (unsigned short*)take(nWC * 2);
  unsigned short* Wcl = (unsigned short*)take(nWC * 2);
  unsigned short* h1h = (unsigned short*)take(nH * 2);
  unsigned short* h1l = (unsigned short*)take(nH * 2);
  float* b1s = (float*)take((size_t)FH * 4);
  float* b2s = (float*)take((size_t)FH * 4);

  if (ws_size < off) return;  // ws too small: bail (validation will flag it)

  // --- preprocessing: fp32 -> bf16 hi/lo splits + bias sums ---
  k_split<<<2048, 256, 0, stream>>>(x,  xh,  xl,  (long)(nBD / 4));
  k_split<<<2048, 256, 0, stream>>>(W1, W1h, W1l, (long)(nW1 / 4));
  k_split<<<2048, 256, 0, stream>>>(W2, W2h, W2l, (long)(nW2 / 4));
  k_split<<<2048, 256, 0, stream>>>(Wc, Wch, Wcl, (long)(nWC / 4));
  k_addbias<<<FH / 256, 256, 0, stream>>>(bi1, bh1, b1s, FH);
  k_addbias<<<FH / 256, 256, 0, stream>>>(bi2, bh2, b2s, FH);

  // --- layer 1: x[8192,1024] -> h1[8192,2048] ---
  k_layer<<<dim3(B / BM, H / BN), 256, 0, stream>>>(xh, xl, W1h, W1l, b1s, h1h, h1l, D, H);
  // --- layer 2: h1 -> h2 (h2 aliases x/W1 splits, now dead) ---
  k_layer<<<dim3(B / BM, H / BN), 256, 0, stream>>>(h1h, h1l, W2h, W2l, b2s, h2h, h2l, H, H);
  // --- classifier: h2 -> out[8192,1000] ---
  k_cls<<<dim3(B / BM, (C + BN - 1) / BN), 256, 0, stream>>>(h2h, h2l, Wch, Wcl, bc, out, H, C);
}

// Round 4
// 1163.578 us; speedup vs baseline: 4.8682x; 4.8682x over previous
//
#include <hip/hip_runtime.h>
#include <hip/hip_bf16.h>
#include <cstdint>
#include <cstddef>

// ============================================================================
// LSTM (seq_len=1, h0=c0=0) -> 3 GEMMs + elementwise:
//   L1 : gates1 = x  @ W_ih1^T (+b1)   [8192,1024] x [8192,1024]^T  (i,g,o only)
//   L2 : gates2 = h1 @ W_ih2^T (+b2)   K=2048
//   CLS: out    = h2 @ W_cls^T + b_cls [8192,1000]
// f-gate skipped (c0=0 => f*c0=0). W_hh1/W_hh2 unused (h0=0).
// fp32 emulated as bf16 hi+lo split, 3 MFMA products -> rel err ~2^-17.
//
// R4: revert R3's launch_bounds(256,4) on k_layer -> (256,2). R3 forced the
// unified VGPR+AGPR budget to 128 while the kernel needs ~188 (96 acc AGPRs),
// so the compiler SPILLED THE ACCUMULATORS (VGPR_Count 92->64, FETCH 0.55->7.1
// GB, WRITE 72MB->9.7GB, MfmaUtil 49->8.7%, 6x slower). Keep R3's XOR chunk
// swizzle (verified: SQ_LDS_BANK_CONFLICT = 0, was 8.4e7 = 23% of cycles).
// ============================================================================

typedef __bf16 bf16x8 __attribute__((ext_vector_type(8)));
typedef float f32x4 __attribute__((ext_vector_type(4)));

#define DI __device__ __forceinline__

DI unsigned short bf16_rne(float f) {
  unsigned u = __float_as_uint(f);
  unsigned r = (u + 0x7fffu + ((u >> 16) & 1u)) >> 16;
  return (unsigned short)r;
}
DI float bf16_f(unsigned short h) { return __uint_as_float((unsigned)h << 16); }
DI float sigmoid_f(float x) { return 1.0f / (1.0f + __expf(-x)); }
DI float tanh_f(float x) {
  float e = __expf(2.0f * x);
  return (e - 1.0f) / (e + 1.0f);
}

// LDS addressing: row-major [row][32 bf16], 16B chunk index XOR-swizzled by
// row bits. Returns offset in shorts. chunk in 0..3. Verified conflict-free
// (R3: SQ_LDS_BANK_CONFLICT = 0).
DI int swz(int row, int chunk) {
  return row * 32 + (((chunk ^ (row >> 1)) & 3) << 3);
}

// ---------------------------------------------------------------------------
// fp32 -> (bf16 hi, bf16 lo) split, vectorized float4. Memory-bound.
// ---------------------------------------------------------------------------
__global__ void k_split(const float* __restrict__ s, unsigned short* __restrict__ hi,
                        unsigned short* __restrict__ lo, long n4) {
  long i = (long)blockIdx.x * blockDim.x + threadIdx.x;
  long st = (long)gridDim.x * blockDim.x;
  for (; i < n4; i += st) {
    float4 v = ((const float4*)s)[i];
    ushort4 h, l;
    h.x = bf16_rne(v.x); l.x = bf16_rne(v.x - bf16_f(h.x));
    h.y = bf16_rne(v.y); l.y = bf16_rne(v.y - bf16_f(h.y));
    h.z = bf16_rne(v.z); l.z = bf16_rne(v.z - bf16_f(h.z));
    h.w = bf16_rne(v.w); l.w = bf16_rne(v.w - bf16_f(h.w));
    ((ushort4*)hi)[i] = h;
    ((ushort4*)lo)[i] = l;
  }
}

__global__ void k_addbias(const float* __restrict__ a, const float* __restrict__ b,
                          float* __restrict__ o, int n) {
  int i = blockIdx.x * blockDim.x + threadIdx.x;
  if (i < n) o[i] = a[i] + b[i];
}

// ---------------------------------------------------------------------------
// Fused LSTM layer: h = tanh( sigmoid(o) * tanh( sigmoid(i)*tanh(g) ) )
// 128x64 h-tile, 4 waves 2x2, wave tile 64x32 per gate, BK=32.
// launch_bounds(256,2): needs ~188 unified VGPR+AGPR; (256,4) spills acc.
// ---------------------------------------------------------------------------
#define BM 128
#define BN 64

__global__ __launch_bounds__(256, 2) void k_layer(
    const unsigned short* __restrict__ Ah, const unsigned short* __restrict__ Al,
    const unsigned short* __restrict__ Wh, const unsigned short* __restrict__ Wl,
    const float* __restrict__ bsum,
    unsigned short* __restrict__ Hh, unsigned short* __restrict__ Hl,
    int K, int H) {
  __shared__ alignas(16) unsigned short sAh[BM * 32];      // 8 KB
  __shared__ alignas(16) unsigned short sAl[BM * 32];      // 8 KB
  __shared__ alignas(16) unsigned short sWh[3 * BN * 32];  // 12 KB
  __shared__ alignas(16) unsigned short sWl[3 * BN * 32];  // 12 KB

  const int tid = threadIdx.x;
  const int l = tid & 63;
  const int wid = tid >> 6;
  const int wr = wid >> 1, wc = wid & 1;
  const int lr = l & 15;
  const int lch = l >> 4;  // 16B chunk index along K, 0..3

  const int m0 = blockIdx.x * BM;
  const int n0 = blockIdx.y * BN;

  f32x4 acc[3][4][2] = {};

  for (int k0 = 0; k0 < K; k0 += 32) {
    __syncthreads();  // previous compute done before overwrite
    // --- stage A tile: 128 rows x 32 cols, hi+lo (swizzled write) ---
#pragma unroll
    for (int rep = 0; rep < 2; ++rep) {
      int c = tid + rep * 256;
      int row = c >> 2, ch = c & 3;
      size_t ga = (size_t)(m0 + row) * K + k0 + ch * 8;
      int off = swz(row, ch);
      *(int4*)&sAh[off] = *(const int4*)&Ah[ga];
      *(int4*)&sAl[off] = *(const int4*)&Al[ga];
    }
    // --- stage W tile: 3 gates x 64 rows x 32 cols, hi+lo ---
#pragma unroll
    for (int rep = 0; rep < 3; ++rep) {
      int c = tid + rep * 256;
      int grow = c >> 2, ch = c & 3;
      int gate = grow >> 6, row = grow & 63;
      int gofs = gate ? (gate + 1) * H : 0;  // i:0, g:2H, o:3H
      size_t ga = (size_t)(gofs + n0 + row) * K + k0 + ch * 8;
      int off = swz(grow, ch);
      *(int4*)&sWh[off] = *(const int4*)&Wh[ga];
      *(int4*)&sWl[off] = *(const int4*)&Wl[ga];
    }
    __syncthreads();
    // --- fragments (swizzled read) + MFMA ---
    bf16x8 ah[4], al[4];
#pragma unroll
    for (int m = 0; m < 4; ++m) {
      int off = swz(wr * 64 + m * 16 + lr, lch);
      ah[m] = *(const bf16x8*)&sAh[off];
      al[m] = *(const bf16x8*)&sAl[off];
    }
#pragma unroll
    for (int g = 0; g < 3; ++g) {
      bf16x8 bh[2], bl[2];
#pragma unroll
      for (int n = 0; n < 2; ++n) {
        int off = swz(g * BN + wc * 32 + n * 16 + lr, lch);
        bh[n] = *(const bf16x8*)&sWh[off];
        bl[n] = *(const bf16x8*)&sWl[off];
      }
#pragma unroll
      for (int m = 0; m < 4; ++m)
#pragma unroll
        for (int n = 0; n < 2; ++n) {
          acc[g][m][n] = __builtin_amdgcn_mfma_f32_16x16x32_bf16(ah[m], bh[n], acc[g][m][n], 0, 0, 0);
          acc[g][m][n] = __builtin_amdgcn_mfma_f32_16x16x32_bf16(ah[m], bl[n], acc[g][m][n], 0, 0, 0);
          acc[g][m][n] = __builtin_amdgcn_mfma_f32_16x16x32_bf16(al[m], bh[n], acc[g][m][n], 0, 0, 0);
        }
    }
  }

  // --- epilogue: gates -> h, split h to hi/lo bf16 for the next GEMM ---
  // C/D layout (m89): col = lane&15, row = (lane>>4)*4 + reg
#pragma unroll
  for (int m = 0; m < 4; ++m)
#pragma unroll
    for (int n = 0; n < 2; ++n) {
      int rowl = wr * 64 + m * 16 + (l >> 4) * 4;
      int coll = wc * 32 + n * 16 + lr;
      int col = n0 + coll;
      float bi = bsum[col];
      float bg = bsum[2 * H + col];
      float bo = bsum[3 * H + col];
#pragma unroll
      for (int v = 0; v < 4; ++v) {
        float gi = acc[0][m][n][v] + bi;
        float gg = acc[1][m][n][v] + bg;
        float go = acc[2][m][n][v] + bo;
        float c = sigmoid_f(gi) * tanh_f(gg);          // c = i*g (c0 = 0)
        float h = tanh_f(sigmoid_f(go) * tanh_f(c));   // tanh(o*tanh(c))
        size_t idx = (size_t)(m0 + rowl + v) * H + col;
        unsigned short hh = bf16_rne(h);
        Hh[idx] = hh;
        Hl[idx] = bf16_rne(h - bf16_f(hh));
      }
    }
}

// ---------------------------------------------------------------------------
// Classifier: out = h2 @ W_cls^T + b_cls, fp32 out, N=1000 (guarded)
// ~110 regs (32 acc) -> (256,3) budget 170 is safe, no spill.
// ---------------------------------------------------------------------------
__global__ __launch_bounds__(256, 3) void k_cls(
    const unsigned short* __restrict__ Ah, const unsigned short* __restrict__ Al,
    const unsigned short* __restrict__ Wh, const unsigned short* __restrict__ Wl,
    const float* __restrict__ bias, float* __restrict__ out,
    int K, int N) {
  __shared__ alignas(16) unsigned short sAh[BM * 32];
  __shared__ alignas(16) unsigned short sAl[BM * 32];
  __shared__ alignas(16) unsigned short sWh[BN * 32];
  __shared__ alignas(16) unsigned short sWl[BN * 32];

  const int tid = threadIdx.x;
  const int l = tid & 63;
  const int wid = tid >> 6;
  const int wr = wid >> 1, wc = wid & 1;
  const int lr = l & 15;
  const int lch = l >> 4;

  const int m0 = blockIdx.x * BM;
  const int n0 = blockIdx.y * BN;

  f32x4 acc[4][2] = {};

  for (int k0 = 0; k0 < K; k0 += 32) {
    __syncthreads();
#pragma unroll
    for (int rep = 0; rep < 2; ++rep) {
      int c = tid + rep * 256;
      int row = c >> 2, ch = c & 3;
      size_t ga = (size_t)(m0 + row) * K + k0 + ch * 8;
      int off = swz(row, ch);
      *(int4*)&sAh[off] = *(const int4*)&Ah[ga];
      *(int4*)&sAl[off] = *(const int4*)&Al[ga];
    }
    {  // W: 64 rows x 4 chunks = 256 chunks (1 rep), guard rows >= N
      int row = tid >> 2, ch = tid & 3;
      int rg = n0 + row;
      int off = swz(row, ch);
      int4 z = {0, 0, 0, 0};
      if (rg < N) {
        size_t ga = (size_t)rg * K + k0 + ch * 8;
        *(int4*)&sWh[off] = *(const int4*)&Wh[ga];
        *(int4*)&sWl[off] = *(const int4*)&Wl[ga];
      } else {
        *(int4*)&sWh[off] = z;
        *(int4*)&sWl[off] = z;
      }
    }
    __syncthreads();
    bf16x8 ah[4], al[4];
#pragma unroll
    for (int m = 0; m < 4; ++m) {
      int off = swz(wr * 64 + m * 16 + lr, lch);
      ah[m] = *(const bf16x8*)&sAh[off];
      al[m] = *(const bf16x8*)&sAl[off];
    }
    bf16x8 bh[2], bl[2];
#pragma unroll
    for (int n = 0; n < 2; ++n) {
      int off = swz(wc * 32 + n * 16 + lr, lch);
      bh[n] = *(const bf16x8*)&sWh[off];
      bl[n] = *(const bf16x8*)&sWl[off];
    }
#pragma unroll
    for (int m = 0; m < 4; ++m)
#pragma unroll
      for (int n = 0; n < 2; ++n) {
        acc[m][n] = __builtin_amdgcn_mfma_f32_16x16x32_bf16(ah[m], bh[n], acc[m][n], 0, 0, 0);
        acc[m][n] = __builtin_amdgcn_mfma_f32_16x16x32_bf16(ah[m], bl[n], acc[m][n], 0, 0, 0);
        acc[m][n] = __builtin_amdgcn_mfma_f32_16x16x32_bf16(al[m], bh[n], acc[m][n], 0, 0, 0);
      }
  }

#pragma unroll
  for (int m = 0; m < 4; ++m)
#pragma unroll
    for (int n = 0; n < 2; ++n) {
      int rowl = wr * 64 + m * 16 + (l >> 4) * 4;
      int coll = wc * 32 + n * 16 + lr;
      int col = n0 + coll;
      float bv = (col < N) ? bias[col] : 0.0f;
#pragma unroll
      for (int v = 0; v < 4; ++v) {
        if (col < N) {
          out[(size_t)(m0 + rowl + v) * N + col] = acc[m][n][v] + bv;
        }
      }
    }
}

// ---------------------------------------------------------------------------
extern "C" void kernel_launch(void* const* d_in, const int* in_sizes, int n_in,
                              void* d_out, int out_size, void* d_ws, size_t ws_size,
                              hipStream_t stream) {
  const int B = 8192, D = 1024, H = 2048, C = 1000;
  const int FH = 4 * H;

  const float* x   = (const float*)d_in[0];
  const float* W1  = (const float*)d_in[1];
  const float* bi1 = (const float*)d_in[3];
  const float* bh1 = (const float*)d_in[4];
  const float* W2  = (const float*)d_in[5];
  const float* bi2 = (const float*)d_in[7];
  const float* bh2 = (const float*)d_in[8];
  const float* Wc  = (const float*)d_in[9];
  const float* bc  = (const float*)d_in[10];
  float* out = (float*)d_out;

  // workspace layout (bytes, 256B aligned)
  char* ws = (char*)d_ws;
  size_t off = 0;
  auto take = [&](size_t bytes) -> char* {
    char* p = ws + off;
    off = (off + bytes + 255) & ~(size_t)255;
    return p;
  };
  const size_t nBD = (size_t)B * D;   // 8.39M
  const size_t nW1 = (size_t)FH * D;  // 8.39M
  const size_t nW2 = (size_t)FH * H;  // 16.8M
  const size_t nWC = (size_t)C * H;   // 2.05M
  const size_t nH  = (size_t)B * H;   // 16.8M

  // x + W1 splits are dead after L1; h2 (written by L2, read by CLS) aliases
  // that region. Stream ordering guarantees no hazard.
  char* region0 = take(nBD * 2 * 2 + nW1 * 2 * 2 + 1024);  // xh,xl,W1h,W1l | h2h,h2l
  unsigned short* xh  = (unsigned short*)region0;
  unsigned short* xl  = xh + nBD;
  unsigned short* W1h = xl + nBD;
  unsigned short* W1l = W1h + nW1;
  unsigned short* h2h = (unsigned short*)region0;          // alias (after L1)
  unsigned short* h2l = h2h + nH;

  unsigned short* W2h = (unsigned short*)take(nW2 * 2);
  unsigned short* W2l = (unsigned short*)take(nW2 * 2);
  unsigned short* Wch = (unsigned short*)take(nWC * 2);
  unsigned short* Wcl = (unsigned short*)take(nWC * 2);
  unsigned short* h1h = (unsigned short*)take(nH * 2);
  unsigned short* h1l = (unsigned short*)take(nH * 2);
  float* b1s = (float*)take((size_t)FH * 4);
  float* b2s = (float*)take((size_t)FH * 4);

  if (ws_size < off) return;  // ws too small: bail (validation will flag it)

  // --- preprocessing: fp32 -> bf16 hi/lo splits + bias sums ---
  k_split<<<2048, 256, 0, stream>>>(x,  xh,  xl,  (long)(nBD / 4));
  k_split<<<2048, 256, 0, stream>>>(W1, W1h, W1l, (long)(nW1 / 4));
  k_split<<<2048, 256, 0, stream>>>(W2, W2h, W2l, (long)(nW2 / 4));
  k_split<<<2048, 256, 0, stream>>>(Wc, Wch, Wcl, (long)(nWC / 4));
  k_addbias<<<FH / 256, 256, 0, stream>>>(bi1, bh1, b1s, FH);
  k_addbias<<<FH / 256, 256, 0, stream>>>(bi2, bh2, b2s, FH);

  // --- layer 1: x[8192,1024] -> h1[8192,2048] ---
  k_layer<<<dim3(B / BM, H / BN), 256, 0, stream>>>(xh, xl, W1h, W1l, b1s, h1h, h1l, D, H);
  // --- layer 2: h1 -> h2 (h2 aliases x/W1 splits, now dead) ---
  k_layer<<<dim3(B / BM, H / BN), 256, 0, stream>>>(h1h, h1l, W2h, W2l, b2s, h2h, h2l, H, H);
  // --- classifier: h2 -> out[8192,1000] ---
  k_cls<<<dim3(B / BM, (C + BN - 1) / BN), 256, 0, stream>>>(h2h, h2l, Wch, Wcl, bc, out, H, C);
}